// Round 8
// baseline (39.019 us; speedup 1.0000x reference)
//
#include <hip/hip_runtime.h>

typedef unsigned short ushort_t;
typedef unsigned int uint_t;
typedef __attribute__((ext_vector_type(8))) short short8;
typedef __attribute__((ext_vector_type(4))) float f32x4;

#define IN_DIM 256
#define OUT_DIM 256
#define BATCH 512
#define NSPL 11                  // GRID_SIZE + K bases
#define KSLOT 12                 // 11 bases + 1 silu/residual slot
#define CHUNK_I 64               // inputs per K-chunk
#define KC (CHUNK_I * KSLOT)     // 768 K-slots per chunk
#define LSTRIDE (KC + 8)         // 776 elems -> 1552B row stride (=16 mod 128B: bank-optimal b128)

__device__ __forceinline__ ushort_t f2bf(float f) {
  union { float f; uint_t i; } c; c.f = f;
  uint_t u = c.i;
  u = u + 0x7FFFu + ((u >> 16) & 1u);   // round-to-nearest-even
  return (ushort_t)(u >> 16);
}

// ONE kernel, 512 blocks x 256 threads, ZERO cross-block sync.
// Block = one 16x16 output tile. Per K-chunk (64 inputs = 768 K-slots):
//   build A-subtile (closed-form cubic B-spline + silu) and W-subtile
//   (uw*coef + rw slot) directly into LDS, barrier, split-K MFMA (4 waves x 192),
//   barrier. After 4 chunks: LDS reduce across waves, write out.
__global__ __launch_bounds__(256, 2) void fused(const float* __restrict__ x,
                                                const float* __restrict__ coef,
                                                const float* __restrict__ rw,
                                                const float* __restrict__ uw,
                                                float* __restrict__ out) {
  __shared__ __attribute__((aligned(16))) ushort_t As[16 * LSTRIDE];
  __shared__ __attribute__((aligned(16))) ushort_t Ws[16 * LSTRIDE];
  __shared__ f32x4 red[3][64];

  const int tid = threadIdx.x;
  const int lane = tid & 63;
  const int w = tid >> 6;                 // wave 0..3 (also K-slice owner in MFMA)
  const int B = blockIdx.x;
  const int b0 = (B & 31) * 16;           // M tile
  const int o0 = (B >> 5) * 16;           // N tile
  const int mn = lane & 15;
  const int klane = (lane >> 4) * 8;

  const int rq = tid >> 6;                // row quarter 0..3
  const int il = tid & 63;                // i within chunk

  f32x4 acc = {0.f, 0.f, 0.f, 0.f};

  for (int ci = 0; ci < 4; ++ci) {
    const int ibase = ci * CHUNK_I;

    // ---- build A sub-tile: rows b0..b0+15, inputs ibase..ibase+63 ----
#pragma unroll
    for (int p = 0; p < 4; ++p) {
      const int row = rq + p * 4;                      // 0..15
      const int i = ibase + il;
      const float xf = x[(b0 + row) * IN_DIM + i];

      // knot interval J = floor((x+1.75)*4); u in [0,1); nonzero bases g = J-3..J
      const float t = (xf + 1.75f) * 4.0f;
      const float fJ = floorf(t);
      const int J = (int)fJ;
      const float u = t - fJ;
      const bool inr = (J >= 0) && (J <= 13);

      const float u2 = u * u;
      const float u3 = u2 * u;
      const float um = 1.0f - u;
      const float n0 = um * um * um * (1.0f / 6.0f);
      const float n1 = 0.5f * u3 - u2 + (4.0f / 6.0f);
      const float n2 = -0.5f * u3 + 0.5f * u2 + 0.5f * u + (1.0f / 6.0f);
      const float n3 = u3 * (1.0f / 6.0f);
      const float silu = xf / (1.0f + __expf(-xf));

      ushort_t v[KSLOT];
#pragma unroll
      for (int g = 0; g < NSPL; ++g) {
        const int k = g - J + 3;
        float val = 0.0f;
        if (inr) {
          if (k == 0) val = n0;
          else if (k == 1) val = n1;
          else if (k == 2) val = n2;
          else if (k == 3) val = n3;
        }
        v[g] = f2bf(val);
      }
      v[11] = f2bf(silu);

      uint_t* dst = (uint_t*)&As[row * LSTRIDE + il * KSLOT];
#pragma unroll
      for (int j = 0; j < 6; ++j) dst[j] = (uint_t)v[2 * j] | ((uint_t)v[2 * j + 1] << 16);
    }

    // ---- build W sub-tile: rows o0..o0+15, inputs ibase..ibase+63 ----
#pragma unroll
    for (int p = 0; p < 4; ++p) {
      const int row = rq + p * 4;
      const int i = ibase + il;
      const size_t oi = (size_t)(o0 + row) * IN_DIM + i;
      const float us = uw[oi];
      const float r = rw[oi];
      const float* c = coef + oi * NSPL;

      ushort_t v[KSLOT];
#pragma unroll
      for (int g = 0; g < NSPL; ++g) v[g] = f2bf(us * c[g]);
      v[11] = f2bf(r);

      uint_t* dst = (uint_t*)&Ws[row * LSTRIDE + il * KSLOT];
#pragma unroll
      for (int j = 0; j < 6; ++j) dst[j] = (uint_t)v[2 * j] | ((uint_t)v[2 * j + 1] << 16);
    }

    __syncthreads();

    // ---- MFMA: wave w owns K-slice [w*192, w*192+192) of this chunk ----
    const int kb = w * 192;
#pragma unroll
    for (int s = 0; s < 6; ++s) {
      const int k = kb + s * 32 + klane;
      short8 af = *(const short8*)&As[mn * LSTRIDE + k];
      short8 bfr = *(const short8*)&Ws[mn * LSTRIDE + k];
      acc = __builtin_amdgcn_mfma_f32_16x16x32_bf16(af, bfr, acc, 0, 0, 0);
    }

    __syncthreads();   // protect next chunk's overwrite of As/Ws
  }

  // ---- cross-wave split-K reduce, then write ----
  if (w > 0) red[w - 1][lane] = acc;
  __syncthreads();

  if (w == 0) {
    const f32x4 r0 = red[0][lane];
    const f32x4 r1 = red[1][lane];
    const f32x4 r2 = red[2][lane];
#pragma unroll
    for (int q = 0; q < 4; ++q) acc[q] += r0[q] + r1[q] + r2[q];

    // C/D layout (HW-verified): col = lane&15, row = (lane>>4)*4 + reg
    const int col = o0 + mn;
    const int rbase = b0 + (lane >> 4) * 4;
#pragma unroll
    for (int r = 0; r < 4; ++r) {
      out[(size_t)(rbase + r) * OUT_DIM + col] = acc[r];
    }
  }
}

extern "C" void kernel_launch(void* const* d_in, const int* in_sizes, int n_in,
                              void* d_out, int out_size, void* d_ws, size_t ws_size,
                              hipStream_t stream) {
  const float* x    = (const float*)d_in[0];
  const float* coef = (const float*)d_in[1];
  const float* rw   = (const float*)d_in[2];
  const float* uw   = (const float*)d_in[3];
  float* out = (float*)d_out;

  fused<<<512, 256, 0, stream>>>(x, coef, rw, uw, out);
}